// Round 8
// baseline (1048.318 us; speedup 1.0000x reference)
//
#include <hip/hip_runtime.h>

#define NN 50000
#define D 128
#define EE 600000
#define R 8
#define NR (NN * R)            /* segments, key = dst*R + rel (node-major) */
#define SCAN_CHUNK 1024
#define NSB ((NR + SCAN_CHUNK - 1) / SCAN_CHUNK) /* 391 */
#define KT 36                  /* K tiles: (8*128 + 128)/32 */

typedef unsigned short u16;
typedef unsigned int u32;
typedef __attribute__((ext_vector_type(8))) short bf16x8;
typedef __attribute__((ext_vector_type(4))) float f32x4;

#define RDL(v_, i_) __builtin_amdgcn_readlane((int)(v_), (i_))

__device__ inline u16 f2bf(float f) {
    union { float f; u32 u; } v; v.f = f;
    return (u16)((v.u + 0x7FFFu + ((v.u >> 16) & 1u)) >> 16);
}
__device__ inline u32 cvtpk(float lo, float hi) {
    u32 r;
    asm("v_cvt_pk_bf16_f32 %0, %1, %2" : "=v"(r) : "v"(lo), "v"(hi));
    return r;
}

// ---- prep (round-5 proven versions) ----

// cast x fp32->bf16 pairs AND histogram+rank in one dispatch (6250 blocks)
__global__ __launch_bounds__(256) void prep2_kernel(const float4* __restrict__ x,
                                                    u32* __restrict__ xb,
                                                    const int* __restrict__ dst,
                                                    const int* __restrict__ et,
                                                    int* __restrict__ cnt,
                                                    int* __restrict__ rk) {
    const int i = blockIdx.x * 256 + threadIdx.x;  // < NN*32 exactly
    const float4 v = x[i];
    if (i < EE) rk[i] = atomicAdd(&cnt[dst[i] * R + et[i]], 1);
    xb[i * 2] = (u32)f2bf(v.x) | ((u32)f2bf(v.y) << 16);
    xb[i * 2 + 1] = (u32)f2bf(v.z) | ((u32)f2bf(v.w) << 16);
}

__global__ __launch_bounds__(256) void scanA(const int* __restrict__ cnt,
                                             int* __restrict__ off,
                                             int* __restrict__ bsum) {
    __shared__ int ts[256];
    const int b = blockIdx.x, t = threadIdx.x;
    const int base = b * SCAN_CHUNK + t * 4;
    int v0 = 0, v1 = 0, v2 = 0, v3 = 0;
    if (base + 3 < NR) {
        int4 q = *(const int4*)(cnt + base);
        v0 = q.x; v1 = q.y; v2 = q.z; v3 = q.w;
    } else {
        if (base < NR) v0 = cnt[base];
        if (base + 1 < NR) v1 = cnt[base + 1];
        if (base + 2 < NR) v2 = cnt[base + 2];
    }
    const int s = v0 + v1 + v2 + v3;
    ts[t] = s;
    __syncthreads();
    for (int d = 1; d < 256; d <<= 1) {
        int x = (t >= d) ? ts[t - d] : 0;
        __syncthreads();
        ts[t] += x;
        __syncthreads();
    }
    const int excl = ts[t] - s;
    if (base < NR) off[base] = excl;
    if (base + 1 < NR) off[base + 1] = excl + v0;
    if (base + 2 < NR) off[base + 2] = excl + v0 + v1;
    if (base + 3 < NR) off[base + 3] = excl + v0 + v1 + v2;
    if (t == 255) bsum[b] = ts[255];
}

__global__ __launch_bounds__(256) void scanBC(int* __restrict__ off,
                                              const int* __restrict__ bsum) {
    __shared__ int red[256];
    const int b = blockIdx.x, t = threadIdx.x;
    int p = 0;
    for (int i = t; i < b; i += 256) p += bsum[i];
    red[t] = p;
    __syncthreads();
    for (int d = 128; d > 0; d >>= 1) {
        if (t < d) red[t] += red[t + d];
        __syncthreads();
    }
    const int add = red[0];
    const int base = b * SCAN_CHUNK + t * 4;
#pragma unroll
    for (int j = 0; j < 4; ++j)
        if (base + j < NR) off[base + j] += add;
    if (b == 0 && t == 0) off[NR] = EE;
}

__global__ __launch_bounds__(256) void place2_kernel(const int* __restrict__ src,
                                                     const int* __restrict__ dst,
                                                     const int* __restrict__ et,
                                                     const int* __restrict__ off,
                                                     const int* __restrict__ rk,
                                                     u32* __restrict__ epk, int E) {
    int e = blockIdx.x * 256 + threadIdx.x;
    if (e < E) {
        const int r = et[e];
        const int p = off[dst[e] * R + r] + rk[e];
        epk[p] = ((u32)src[e] << 3) | (u32)r;
    }
}

// ---- pack both layers' B = [W_1..W_8; root] into MFMA B-frag order:
// [kt(36)][g(8)][lane(64)][j(8)], col = g*16+(lane&15), k = kt*32+(lane>>4)*8+j.
// Also zero cnt_i (must precede prep2's atomics; dispatch boundary). ----
__global__ __launch_bounds__(256) void bprep2_kernel(const float* __restrict__ w1,
                                                     const float* __restrict__ root1,
                                                     u16* __restrict__ Bf1,
                                                     const float* __restrict__ w2,
                                                     const float* __restrict__ root2,
                                                     u16* __restrict__ Bf2,
                                                     int4* __restrict__ cntz) {
    int gidx = blockIdx.x * 256 + threadIdx.x;  // over 2*36*8*64 = 36864
    for (int i = gidx; i < NR / 4; i += 36864)
        cntz[i] = make_int4(0, 0, 0, 0);
    if (gidx >= 2 * KT * 8 * 64) return;
    const int layer = gidx / (KT * 8 * 64);
    const int idx = gidx - layer * (KT * 8 * 64);
    const float* w = layer ? w2 : w1;
    const float* root = layer ? root2 : root1;
    u16* Bfrag = layer ? Bf2 : Bf1;
    const int lane = idx & 63;
    const int g = (idx >> 6) & 7;
    const int kt = idx >> 9;  // 0..35
    const int col = g * 16 + (lane & 15);
    const int kbase = kt * 32 + (lane >> 4) * 8;
    u16* o = Bfrag + (size_t)idx * 8;
#pragma unroll
    for (int j = 0; j < 8; ++j) {
        const int k = kbase + j;
        float v = (k < R * D) ? w[(size_t)(k >> 7) * (D * D) + (size_t)(k & 127) * D + col]
                              : root[(size_t)(k - R * D) * D + col];
        o[j] = f2bf(v);
    }
}

// ---- fused RGCN layer (round 8: ds_add_f32 accumulation, XOR swizzle FIXED) ----
// Round-7 bug: swizzle was applied as an ADDITIVE base offset; its bits (2-4)
// carry with lane's bits -> node 7/15 rows overflowed into neighbors and (rel
// 8, node 15) wrote past Fs entirely -> absmax 320. Fix: XOR the COLUMN index
// (col = lane ^ swz, swz=(node&7)<<2): bijective within the 64-col half-row.
// Read side mirrors it: float4 at column base c (mult of 4) sits at c ^ swz
// (XOR keeps the 4-group contiguous & aligned).
// Phase 1: LDS f32 accumulator F[9][16][128] (rel-major; rel 8 = root). Per
// edge: rel is SCALAR (uniform epk load) -> slot addr = scalar base + col;
// 2x ds_add_f32 (2-way, free); ~5 VALU/edge, no flush machinery, all edges
// independent. Lo cols [0..63] = even dims, hi [64..127] = odd dims, so
// phase-2 rebuilds bf16 pairs with v_cvt_pk_bf16_f32. Mean scaling deferred
// to phase 2 (per-lane inv[8], static-indexed, full unroll). Phase-2 reads
// spread 16 nodes over 8 disjoint 4-bank groups (2-way, free).
// LDS 74KB -> 2 blocks/CU: acceptable, we are issue-bound not latency-bound.
template <bool OUTBF>
__global__ __launch_bounds__(512, 4) void rgcn_fused(const u32* __restrict__ xb,
                                                     const u16* __restrict__ Bf,
                                                     const int* __restrict__ off,
                                                     const u32* __restrict__ epk,
                                                     const float* __restrict__ bias,
                                                     void* __restrict__ outp) {
    __shared__ float Fs[9 * 16 * 128];   // 73728 B
    __shared__ float inv_lds[16][8];     // 512 B

    const int t = threadIdx.x;
    const int wid = t >> 6;
    const int lane = t & 63;
    const int n0 = blockIdx.x * 16;

    // zero F (empty segments must contribute 0)
    {
        uint4* Fz = (uint4*)Fs;
        for (int i = t; i < 4608; i += 512) Fz[i] = make_uint4(0, 0, 0, 0);
    }
    __syncthreads();

    const int i0 = wid * 2;              // this wave's 2 local node slots
    const int nb = n0 + i0;              // < NN always (50000 = 16*3125)

    // 17 boundaries for 2 nodes (one clamped load; off[NR] = EE)
    int offv;
    {
        int oi = nb * 8 + lane;
        if (oi > NR) oi = NR;
        offv = off[oi];
    }

    // per-(node,rel) inverse counts -> inv_lds
    {
        const int cnext = __shfl(offv, lane + 1);
        if (lane < 16) {
            const int c = cnext - offv;
            inv_lds[i0 + (lane >> 3)][lane & 7] = (c > 0) ? 1.0f / (float)c : 0.f;
        }
    }

    // root rows -> F rel=8 (plain stores, each slot owned by one wave)
    {
        const u32 rv0 = xb[(size_t)nb * 64 + lane];
        const u32 rv1 = xb[(size_t)(nb + 1) * 64 + lane];
        const int c0 = lane ^ ((i0 & 7) << 2);
        const int c1 = lane ^ (((i0 + 1) & 7) << 2);
        union { u32 u; float f; } lo_, hi_;
        lo_.u = rv0 << 16; hi_.u = rv0 & 0xFFFF0000u;
        Fs[16384 + i0 * 128 + c0] = lo_.f;
        Fs[16384 + i0 * 128 + c0 + 64] = hi_.f;
        lo_.u = rv1 << 16; hi_.u = rv1 & 0xFFFF0000u;
        Fs[16384 + (i0 + 1) * 128 + c1] = lo_.f;
        Fs[16384 + (i0 + 1) * 128 + c1 + 64] = hi_.f;
    }

    const int eA = RDL(offv, 0);
    const int eM = RDL(offv, 8);
    const int eB = RDL(offv, 16);

#define EDGE(q_, v_)                                                           \
    {                                                                          \
        const int fb = (int)((q_) & 7u) * 2048 + nbase;                        \
        union { u32 u; float f; } lo_, hi_;                                    \
        lo_.u = (v_) << 16; hi_.u = (v_) & 0xFFFF0000u;                        \
        atomicAdd(&Fs[fb], lo_.f);                                             \
        atomicAdd(&Fs[fb + 64], hi_.f);                                        \
    }

#define STREAM(NODE, SE, EEND)                                                 \
    {                                                                          \
        const int nbase = (NODE) * 128 + (lane ^ (((NODE) & 7) << 2));         \
        _Pragma("unroll 1")                                                    \
        for (int p = (SE); p < (EEND); p += 8) {                               \
            int j1 = p + 1, j2 = p + 2, j3 = p + 3;                            \
            int j4 = p + 4, j5 = p + 5, j6 = p + 6, j7 = p + 7;                \
            const int jm = (EEND) - 1;                                         \
            if (j1 > jm) j1 = jm; if (j2 > jm) j2 = jm; if (j3 > jm) j3 = jm;  \
            if (j4 > jm) j4 = jm; if (j5 > jm) j5 = jm; if (j6 > jm) j6 = jm;  \
            if (j7 > jm) j7 = jm;                                              \
            const u32 q0 = epk[p], q1 = epk[j1], q2 = epk[j2], q3 = epk[j3];   \
            const u32 q4 = epk[j4], q5 = epk[j5], q6 = epk[j6], q7 = epk[j7];  \
            const u32 v0 = xb[(size_t)(q0 >> 3) * 64 + lane];                  \
            const u32 v1 = xb[(size_t)(q1 >> 3) * 64 + lane];                  \
            const u32 v2 = xb[(size_t)(q2 >> 3) * 64 + lane];                  \
            const u32 v3 = xb[(size_t)(q3 >> 3) * 64 + lane];                  \
            const u32 v4 = xb[(size_t)(q4 >> 3) * 64 + lane];                  \
            const u32 v5 = xb[(size_t)(q5 >> 3) * 64 + lane];                  \
            const u32 v6 = xb[(size_t)(q6 >> 3) * 64 + lane];                  \
            const u32 v7 = xb[(size_t)(q7 >> 3) * 64 + lane];                  \
            EDGE(q0, v0);                                                      \
            if (p + 1 < (EEND)) EDGE(q1, v1);                                  \
            if (p + 2 < (EEND)) EDGE(q2, v2);                                  \
            if (p + 3 < (EEND)) EDGE(q3, v3);                                  \
            if (p + 4 < (EEND)) EDGE(q4, v4);                                  \
            if (p + 5 < (EEND)) EDGE(q5, v5);                                  \
            if (p + 6 < (EEND)) EDGE(q6, v6);                                  \
            if (p + 7 < (EEND)) EDGE(q7, v7);                                  \
        }                                                                      \
    }

    STREAM(i0, eA, eM);
    STREAM(i0 + 1, eM, eB);

#undef EDGE
#undef STREAM
    __syncthreads();

    // ---- phase 2: wave g -> col-tile g; A from F (convert on the fly) ----
    const int g = wid;
    const int node = lane & 15;
    const int quad = lane >> 4;
    const int swz = (node & 7) << 2;
    const int quad4 = quad * 4;
    const int nrow = node * 128;

    float vinv[8];
    {
        const float4 ia = *(const float4*)&inv_lds[node][0];
        const float4 ib = *(const float4*)&inv_lds[node][4];
        vinv[0] = ia.x; vinv[1] = ia.y; vinv[2] = ia.z; vinv[3] = ia.w;
        vinv[4] = ib.x; vinv[5] = ib.y; vinv[6] = ib.z; vinv[7] = ib.w;
    }

    f32x4 acc = {0.f, 0.f, 0.f, 0.f};
    const u16* bp = Bf + ((size_t)g * 64 + lane) * 8;
#pragma unroll
    for (int kt = 0; kt < KT; ++kt) {
        const int rel = kt >> 2, kc = kt & 3;
        const bf16x8 b = *(const bf16x8*)(bp + (size_t)kt * 4096);
        const int cidx = nrow + ((kc * 16 + quad4) ^ swz);
        const float4 lo = *(const float4*)&Fs[cidx + rel * 2048];
        const float4 hi = *(const float4*)&Fs[cidx + rel * 2048 + 64];
        float l0 = lo.x, l1 = lo.y, l2 = lo.z, l3 = lo.w;
        float h0 = hi.x, h1 = hi.y, h2 = hi.z, h3 = hi.w;
        if (rel < 8) {
            const float s = vinv[rel];
            l0 *= s; l1 *= s; l2 *= s; l3 *= s;
            h0 *= s; h1 *= s; h2 *= s; h3 *= s;
        }
        union { u32 q[4]; bf16x8 v; } U;
        U.q[0] = cvtpk(l0, h0); U.q[1] = cvtpk(l1, h1);
        U.q[2] = cvtpk(l2, h2); U.q[3] = cvtpk(l3, h3);
        acc = __builtin_amdgcn_mfma_f32_16x16x32_bf16(U.v, b, acc, 0, 0, 0);
    }

    // ---- epilogue: C row=(lane>>4)*4+q, col=g*16+(lane&15); no tail ----
    const int col = g * 16 + (lane & 15);
    const float bb = bias[col];
#pragma unroll
    for (int q = 0; q < 4; ++q) {
        const int row = n0 + quad * 4 + q;
        const float v = fmaxf(acc[q] + bb, 0.f);
        if (OUTBF)
            ((u16*)outp)[(size_t)row * D + col] = f2bf(v);
        else
            ((float*)outp)[(size_t)row * D + col] = v;
    }
}

extern "C" void kernel_launch(void* const* d_in, const int* in_sizes, int n_in,
                              void* d_out, int out_size, void* d_ws, size_t ws_size,
                              hipStream_t stream) {
    const float* x = (const float*)d_in[0];
    const int* ei = (const int*)d_in[1];
    const int* et = (const int*)d_in[2];
    const float* w1 = (const float*)d_in[3];
    const float* root1 = (const float*)d_in[4];
    const float* b1 = (const float*)d_in[5];
    const float* w2 = (const float*)d_in[6];
    const float* root2 = (const float*)d_in[7];
    const float* b2 = (const float*)d_in[8];
    float* out = (float*)d_out;

    char* ws = (char*)d_ws;
    int* off    = (int*)(ws + 0);                  // (NR+1) ints
    int* cnt_i  = (int*)(ws + 1600512);            // NR ints
    int* rk     = (int*)(ws + 3200512);            // EE ints (edge rank)
    int* bsum   = (int*)(ws + 5600512);            // NSB ints
    u32* epk    = (u32*)(ws + 5604096);            // EE u32 (2.4 MB)
    u32* xb     = (u32*)(ws + 8004096);            // N*64 u32 = 12.8 MB
    u32* h      = (u32*)(ws + 20804096);           // N*64 u32 = 12.8 MB
    u16* Bf1    = (u16*)(ws + 33604096);           // 294912 B
    u16* Bf2    = (u16*)(ws + 33899008);           // 294912 B

    const int* srcp = ei;
    const int* dstp = ei + EE;

    // ---- prep (round-5 structure): pack B + zero cnt; {xcast ∥ hist+rank};
    // scan; place ----
    bprep2_kernel<<<144, 256, 0, stream>>>(w1, root1, Bf1, w2, root2, Bf2,
                                           (int4*)cnt_i);
    prep2_kernel<<<NN * 32 / 256, 256, 0, stream>>>((const float4*)x, xb,
                                                    dstp, et, cnt_i, rk);
    scanA<<<NSB, 256, 0, stream>>>(cnt_i, off, bsum);
    scanBC<<<NSB, 256, 0, stream>>>(off, bsum);
    place2_kernel<<<(EE + 255) / 256, 256, 0, stream>>>(srcp, dstp, et, off, rk,
                                                        epk, EE);

    const int fused_blocks = NN / 16;  // 3125, exact

    // layer 1: xb -> h (bf16)
    rgcn_fused<true><<<fused_blocks, 512, 0, stream>>>(xb, Bf1, off, epk, b1,
                                                       (void*)h);
    // layer 2: h -> out (fp32)
    rgcn_fused<false><<<fused_blocks, 512, 0, stream>>>(h, Bf2, off, epk, b2,
                                                        (void*)out);
}

// Round 9
// 1039.516 us; speedup vs baseline: 1.0085x; 1.0085x over previous
//
#include <hip/hip_runtime.h>

#define NN 50000
#define D 128
#define EE 600000
#define R 8
#define NR (NN * R)            /* segments, key = dst*R + rel (node-major) */
#define SCAN_CHUNK 1024
#define NSB ((NR + SCAN_CHUNK - 1) / SCAN_CHUNK) /* 391 */
#define KT 36                  /* K tiles: (8*128 + 128)/32 */

typedef unsigned short u16;
typedef unsigned int u32;
typedef __attribute__((ext_vector_type(8))) short bf16x8;
typedef __attribute__((ext_vector_type(4))) float f32x4;

#define RDL(v_, i_) __builtin_amdgcn_readlane((int)(v_), (i_))

__device__ inline u16 f2bf(float f) {
    union { float f; u32 u; } v; v.f = f;
    return (u16)((v.u + 0x7FFFu + ((v.u >> 16) & 1u)) >> 16);
}
__device__ inline u32 cvtpk(float lo, float hi) {
    u32 r;
    asm("v_cvt_pk_bf16_f32 %0, %1, %2" : "=v"(r) : "v"(lo), "v"(hi));
    return r;
}
// Native no-return LDS fp add. Plain atomicAdd(__shared__ float*) lowers to a
// CAS retry loop without -munsafe-fp-atomics (round 8: 7.4M LDS "conflict"
// cycles, VALUBusy 6.6%, 475us). unsafeAtomicAdd emits ds_add_f32.
__device__ inline void ds_fadd(float* p, float v) { unsafeAtomicAdd(p, v); }

// ---- prep (round-5 proven versions) ----

// cast x fp32->bf16 pairs AND histogram+rank in one dispatch (6250 blocks)
__global__ __launch_bounds__(256) void prep2_kernel(const float4* __restrict__ x,
                                                    u32* __restrict__ xb,
                                                    const int* __restrict__ dst,
                                                    const int* __restrict__ et,
                                                    int* __restrict__ cnt,
                                                    int* __restrict__ rk) {
    const int i = blockIdx.x * 256 + threadIdx.x;  // < NN*32 exactly
    const float4 v = x[i];
    if (i < EE) rk[i] = atomicAdd(&cnt[dst[i] * R + et[i]], 1);
    xb[i * 2] = (u32)f2bf(v.x) | ((u32)f2bf(v.y) << 16);
    xb[i * 2 + 1] = (u32)f2bf(v.z) | ((u32)f2bf(v.w) << 16);
}

__global__ __launch_bounds__(256) void scanA(const int* __restrict__ cnt,
                                             int* __restrict__ off,
                                             int* __restrict__ bsum) {
    __shared__ int ts[256];
    const int b = blockIdx.x, t = threadIdx.x;
    const int base = b * SCAN_CHUNK + t * 4;
    int v0 = 0, v1 = 0, v2 = 0, v3 = 0;
    if (base + 3 < NR) {
        int4 q = *(const int4*)(cnt + base);
        v0 = q.x; v1 = q.y; v2 = q.z; v3 = q.w;
    } else {
        if (base < NR) v0 = cnt[base];
        if (base + 1 < NR) v1 = cnt[base + 1];
        if (base + 2 < NR) v2 = cnt[base + 2];
    }
    const int s = v0 + v1 + v2 + v3;
    ts[t] = s;
    __syncthreads();
    for (int d = 1; d < 256; d <<= 1) {
        int x = (t >= d) ? ts[t - d] : 0;
        __syncthreads();
        ts[t] += x;
        __syncthreads();
    }
    const int excl = ts[t] - s;
    if (base < NR) off[base] = excl;
    if (base + 1 < NR) off[base + 1] = excl + v0;
    if (base + 2 < NR) off[base + 2] = excl + v0 + v1;
    if (base + 3 < NR) off[base + 3] = excl + v0 + v1 + v2;
    if (t == 255) bsum[b] = ts[255];
}

__global__ __launch_bounds__(256) void scanBC(int* __restrict__ off,
                                              const int* __restrict__ bsum) {
    __shared__ int red[256];
    const int b = blockIdx.x, t = threadIdx.x;
    int p = 0;
    for (int i = t; i < b; i += 256) p += bsum[i];
    red[t] = p;
    __syncthreads();
    for (int d = 128; d > 0; d >>= 1) {
        if (t < d) red[t] += red[t + d];
        __syncthreads();
    }
    const int add = red[0];
    const int base = b * SCAN_CHUNK + t * 4;
#pragma unroll
    for (int j = 0; j < 4; ++j)
        if (base + j < NR) off[base + j] += add;
    if (b == 0 && t == 0) off[NR] = EE;
}

__global__ __launch_bounds__(256) void place2_kernel(const int* __restrict__ src,
                                                     const int* __restrict__ dst,
                                                     const int* __restrict__ et,
                                                     const int* __restrict__ off,
                                                     const int* __restrict__ rk,
                                                     u32* __restrict__ epk, int E) {
    int e = blockIdx.x * 256 + threadIdx.x;
    if (e < E) {
        const int r = et[e];
        const int p = off[dst[e] * R + r] + rk[e];
        epk[p] = ((u32)src[e] << 3) | (u32)r;
    }
}

// ---- pack both layers' B = [W_1..W_8; root] into MFMA B-frag order:
// [kt(36)][g(8)][lane(64)][j(8)], col = g*16+(lane&15), k = kt*32+(lane>>4)*8+j.
// Also zero cnt_i (must precede prep2's atomics; dispatch boundary). ----
__global__ __launch_bounds__(256) void bprep2_kernel(const float* __restrict__ w1,
                                                     const float* __restrict__ root1,
                                                     u16* __restrict__ Bf1,
                                                     const float* __restrict__ w2,
                                                     const float* __restrict__ root2,
                                                     u16* __restrict__ Bf2,
                                                     int4* __restrict__ cntz) {
    int gidx = blockIdx.x * 256 + threadIdx.x;  // over 2*36*8*64 = 36864
    for (int i = gidx; i < NR / 4; i += 36864)
        cntz[i] = make_int4(0, 0, 0, 0);
    if (gidx >= 2 * KT * 8 * 64) return;
    const int layer = gidx / (KT * 8 * 64);
    const int idx = gidx - layer * (KT * 8 * 64);
    const float* w = layer ? w2 : w1;
    const float* root = layer ? root2 : root1;
    u16* Bfrag = layer ? Bf2 : Bf1;
    const int lane = idx & 63;
    const int g = (idx >> 6) & 7;
    const int kt = idx >> 9;  // 0..35
    const int col = g * 16 + (lane & 15);
    const int kbase = kt * 32 + (lane >> 4) * 8;
    u16* o = Bfrag + (size_t)idx * 8;
#pragma unroll
    for (int j = 0; j < 8; ++j) {
        const int k = kbase + j;
        float v = (k < R * D) ? w[(size_t)(k >> 7) * (D * D) + (size_t)(k & 127) * D + col]
                              : root[(size_t)(k - R * D) * D + col];
        o[j] = f2bf(v);
    }
}

// ---- fused RGCN layer (round 9: ds_add_f32 via unsafeAtomicAdd) ----
// Phase 1: LDS f32 accumulator F[9][16][128] (rel-major; rel 8 = root). Per
// edge: rel is SCALAR (uniform epk load) -> slot addr = scalar base + col;
// 2x native ds_add_f32, fire-and-forget (no RAW chain, all edges fully
// independent); ~6 issue-ops/edge, no segment-flush machinery. Column XOR
// swizzle col = lane ^ ((node&7)<<2) (bijective within the 64-col half-row,
// verified round 8); lo cols [0..63] = even dims, hi [64..127] = odd dims,
// phase-2 rebuilds bf16 pairs with v_cvt_pk_bf16_f32. Mean scaling deferred
// to phase 2 (per-lane inv[8], static-indexed, full unroll). Slot ownership
// is wave-private (node owned by one wave), so the "atomic" is only needed
// to get the native fadd instruction, not for contention.
// LDS 74KB -> 2 blocks/CU: acceptable while issue/latency-bound.
template <bool OUTBF>
__global__ __launch_bounds__(512, 4) void rgcn_fused(const u32* __restrict__ xb,
                                                     const u16* __restrict__ Bf,
                                                     const int* __restrict__ off,
                                                     const u32* __restrict__ epk,
                                                     const float* __restrict__ bias,
                                                     void* __restrict__ outp) {
    __shared__ float Fs[9 * 16 * 128];   // 73728 B
    __shared__ float inv_lds[16][8];     // 512 B

    const int t = threadIdx.x;
    const int wid = t >> 6;
    const int lane = t & 63;
    const int n0 = blockIdx.x * 16;

    // zero F (empty segments must contribute 0)
    {
        uint4* Fz = (uint4*)Fs;
        for (int i = t; i < 4608; i += 512) Fz[i] = make_uint4(0, 0, 0, 0);
    }
    __syncthreads();

    const int i0 = wid * 2;              // this wave's 2 local node slots
    const int nb = n0 + i0;              // < NN always (50000 = 16*3125)

    // 17 boundaries for 2 nodes (one clamped load; off[NR] = EE)
    int offv;
    {
        int oi = nb * 8 + lane;
        if (oi > NR) oi = NR;
        offv = off[oi];
    }

    // per-(node,rel) inverse counts -> inv_lds
    {
        const int cnext = __shfl(offv, lane + 1);
        if (lane < 16) {
            const int c = cnext - offv;
            inv_lds[i0 + (lane >> 3)][lane & 7] = (c > 0) ? 1.0f / (float)c : 0.f;
        }
    }

    // root rows -> F rel=8 (plain stores, each slot owned by one wave)
    {
        const u32 rv0 = xb[(size_t)nb * 64 + lane];
        const u32 rv1 = xb[(size_t)(nb + 1) * 64 + lane];
        const int c0 = lane ^ ((i0 & 7) << 2);
        const int c1 = lane ^ (((i0 + 1) & 7) << 2);
        union { u32 u; float f; } lo_, hi_;
        lo_.u = rv0 << 16; hi_.u = rv0 & 0xFFFF0000u;
        Fs[16384 + i0 * 128 + c0] = lo_.f;
        Fs[16384 + i0 * 128 + c0 + 64] = hi_.f;
        lo_.u = rv1 << 16; hi_.u = rv1 & 0xFFFF0000u;
        Fs[16384 + (i0 + 1) * 128 + c1] = lo_.f;
        Fs[16384 + (i0 + 1) * 128 + c1 + 64] = hi_.f;
    }

    const int eA = RDL(offv, 0);
    const int eM = RDL(offv, 8);
    const int eB = RDL(offv, 16);

#define EDGE(q_, v_)                                                           \
    {                                                                          \
        const int fb = (int)((q_) & 7u) * 2048 + nbase;                        \
        union { u32 u; float f; } lo_, hi_;                                    \
        lo_.u = (v_) << 16; hi_.u = (v_) & 0xFFFF0000u;                        \
        ds_fadd(&Fs[fb], lo_.f);                                               \
        ds_fadd(&Fs[fb + 64], hi_.f);                                          \
    }

#define STREAM(NODE, SE, EEND)                                                 \
    {                                                                          \
        const int nbase = (NODE) * 128 + (lane ^ (((NODE) & 7) << 2));         \
        _Pragma("unroll 1")                                                    \
        for (int p = (SE); p < (EEND); p += 8) {                               \
            int j1 = p + 1, j2 = p + 2, j3 = p + 3;                            \
            int j4 = p + 4, j5 = p + 5, j6 = p + 6, j7 = p + 7;                \
            const int jm = (EEND) - 1;                                         \
            if (j1 > jm) j1 = jm; if (j2 > jm) j2 = jm; if (j3 > jm) j3 = jm;  \
            if (j4 > jm) j4 = jm; if (j5 > jm) j5 = jm; if (j6 > jm) j6 = jm;  \
            if (j7 > jm) j7 = jm;                                              \
            const u32 q0 = epk[p], q1 = epk[j1], q2 = epk[j2], q3 = epk[j3];   \
            const u32 q4 = epk[j4], q5 = epk[j5], q6 = epk[j6], q7 = epk[j7];  \
            const u32 v0 = xb[(size_t)(q0 >> 3) * 64 + lane];                  \
            const u32 v1 = xb[(size_t)(q1 >> 3) * 64 + lane];                  \
            const u32 v2 = xb[(size_t)(q2 >> 3) * 64 + lane];                  \
            const u32 v3 = xb[(size_t)(q3 >> 3) * 64 + lane];                  \
            const u32 v4 = xb[(size_t)(q4 >> 3) * 64 + lane];                  \
            const u32 v5 = xb[(size_t)(q5 >> 3) * 64 + lane];                  \
            const u32 v6 = xb[(size_t)(q6 >> 3) * 64 + lane];                  \
            const u32 v7 = xb[(size_t)(q7 >> 3) * 64 + lane];                  \
            EDGE(q0, v0);                                                      \
            if (p + 1 < (EEND)) EDGE(q1, v1);                                  \
            if (p + 2 < (EEND)) EDGE(q2, v2);                                  \
            if (p + 3 < (EEND)) EDGE(q3, v3);                                  \
            if (p + 4 < (EEND)) EDGE(q4, v4);                                  \
            if (p + 5 < (EEND)) EDGE(q5, v5);                                  \
            if (p + 6 < (EEND)) EDGE(q6, v6);                                  \
            if (p + 7 < (EEND)) EDGE(q7, v7);                                  \
        }                                                                      \
    }

    STREAM(i0, eA, eM);
    STREAM(i0 + 1, eM, eB);

#undef EDGE
#undef STREAM
    __syncthreads();

    // ---- phase 2: wave g -> col-tile g; A from F (convert on the fly) ----
    const int g = wid;
    const int node = lane & 15;
    const int quad = lane >> 4;
    const int swz = (node & 7) << 2;
    const int quad4 = quad * 4;
    const int nrow = node * 128;

    float vinv[8];
    {
        const float4 ia = *(const float4*)&inv_lds[node][0];
        const float4 ib = *(const float4*)&inv_lds[node][4];
        vinv[0] = ia.x; vinv[1] = ia.y; vinv[2] = ia.z; vinv[3] = ia.w;
        vinv[4] = ib.x; vinv[5] = ib.y; vinv[6] = ib.z; vinv[7] = ib.w;
    }

    f32x4 acc = {0.f, 0.f, 0.f, 0.f};
    const u16* bp = Bf + ((size_t)g * 64 + lane) * 8;
#pragma unroll
    for (int kt = 0; kt < KT; ++kt) {
        const int rel = kt >> 2, kc = kt & 3;
        const bf16x8 b = *(const bf16x8*)(bp + (size_t)kt * 4096);
        const int cidx = nrow + ((kc * 16 + quad4) ^ swz);
        const float4 lo = *(const float4*)&Fs[cidx + rel * 2048];
        const float4 hi = *(const float4*)&Fs[cidx + rel * 2048 + 64];
        float l0 = lo.x, l1 = lo.y, l2 = lo.z, l3 = lo.w;
        float h0 = hi.x, h1 = hi.y, h2 = hi.z, h3 = hi.w;
        if (rel < 8) {
            const float s = vinv[rel];
            l0 *= s; l1 *= s; l2 *= s; l3 *= s;
            h0 *= s; h1 *= s; h2 *= s; h3 *= s;
        }
        union { u32 q[4]; bf16x8 v; } U;
        U.q[0] = cvtpk(l0, h0); U.q[1] = cvtpk(l1, h1);
        U.q[2] = cvtpk(l2, h2); U.q[3] = cvtpk(l3, h3);
        acc = __builtin_amdgcn_mfma_f32_16x16x32_bf16(U.v, b, acc, 0, 0, 0);
    }

    // ---- epilogue: C row=(lane>>4)*4+q, col=g*16+(lane&15); no tail ----
    const int col = g * 16 + (lane & 15);
    const float bb = bias[col];
#pragma unroll
    for (int q = 0; q < 4; ++q) {
        const int row = n0 + quad * 4 + q;
        const float v = fmaxf(acc[q] + bb, 0.f);
        if (OUTBF)
            ((u16*)outp)[(size_t)row * D + col] = f2bf(v);
        else
            ((float*)outp)[(size_t)row * D + col] = v;
    }
}

extern "C" void kernel_launch(void* const* d_in, const int* in_sizes, int n_in,
                              void* d_out, int out_size, void* d_ws, size_t ws_size,
                              hipStream_t stream) {
    const float* x = (const float*)d_in[0];
    const int* ei = (const int*)d_in[1];
    const int* et = (const int*)d_in[2];
    const float* w1 = (const float*)d_in[3];
    const float* root1 = (const float*)d_in[4];
    const float* b1 = (const float*)d_in[5];
    const float* w2 = (const float*)d_in[6];
    const float* root2 = (const float*)d_in[7];
    const float* b2 = (const float*)d_in[8];
    float* out = (float*)d_out;

    char* ws = (char*)d_ws;
    int* off    = (int*)(ws + 0);                  // (NR+1) ints
    int* cnt_i  = (int*)(ws + 1600512);            // NR ints
    int* rk     = (int*)(ws + 3200512);            // EE ints (edge rank)
    int* bsum   = (int*)(ws + 5600512);            // NSB ints
    u32* epk    = (u32*)(ws + 5604096);            // EE u32 (2.4 MB)
    u32* xb     = (u32*)(ws + 8004096);            // N*64 u32 = 12.8 MB
    u32* h      = (u32*)(ws + 20804096);           // N*64 u32 = 12.8 MB
    u16* Bf1    = (u16*)(ws + 33604096);           // 294912 B
    u16* Bf2    = (u16*)(ws + 33899008);           // 294912 B

    const int* srcp = ei;
    const int* dstp = ei + EE;

    // ---- prep (round-5 structure): pack B + zero cnt; {xcast ∥ hist+rank};
    // scan; place ----
    bprep2_kernel<<<144, 256, 0, stream>>>(w1, root1, Bf1, w2, root2, Bf2,
                                           (int4*)cnt_i);
    prep2_kernel<<<NN * 32 / 256, 256, 0, stream>>>((const float4*)x, xb,
                                                    dstp, et, cnt_i, rk);
    scanA<<<NSB, 256, 0, stream>>>(cnt_i, off, bsum);
    scanBC<<<NSB, 256, 0, stream>>>(off, bsum);
    place2_kernel<<<(EE + 255) / 256, 256, 0, stream>>>(srcp, dstp, et, off, rk,
                                                        epk, EE);

    const int fused_blocks = NN / 16;  // 3125, exact

    // layer 1: xb -> h (bf16)
    rgcn_fused<true><<<fused_blocks, 512, 0, stream>>>(xb, Bf1, off, epk, b1,
                                                       (void*)h);
    // layer 2: h -> out (fp32)
    rgcn_fused<false><<<fused_blocks, 512, 0, stream>>>(h, Bf2, off, epk, b2,
                                                        (void*)out);
}

// Round 10
// 1026.401 us; speedup vs baseline: 1.0214x; 1.0128x over previous
//
#include <hip/hip_runtime.h>

#define NN 50000
#define D 128
#define EE 600000
#define R 8
#define NR (NN * R)            /* segments, key = dst*R + rel (node-major) */
#define SCAN_CHUNK 1024
#define NSB ((NR + SCAN_CHUNK - 1) / SCAN_CHUNK) /* 391 */
#define KT 36                  /* K tiles: (8*128 + 128)/32 */

typedef unsigned short u16;
typedef unsigned int u32;
typedef __attribute__((ext_vector_type(8))) short bf16x8;
typedef __attribute__((ext_vector_type(4))) float f32x4;

#define RDL(v_, i_) __builtin_amdgcn_readlane((int)(v_), (i_))

__device__ inline u16 f2bf(float f) {
    union { float f; u32 u; } v; v.f = f;
    return (u16)((v.u + 0x7FFFu + ((v.u >> 16) & 1u)) >> 16);
}
__device__ inline u32 cvtpk(float lo, float hi) {
    u32 r;
    asm("v_cvt_pk_bf16_f32 %0, %1, %2" : "=v"(r) : "v"(lo), "v"(hi));
    return r;
}
// Native no-return LDS fp add (ds_add_f32).
__device__ inline void ds_fadd(float* p, float v) { unsafeAtomicAdd(p, v); }

// ---- prep (round-5 proven versions) ----

// cast x fp32->bf16 pairs AND histogram+rank in one dispatch (6250 blocks)
__global__ __launch_bounds__(256) void prep2_kernel(const float4* __restrict__ x,
                                                    u32* __restrict__ xb,
                                                    const int* __restrict__ dst,
                                                    const int* __restrict__ et,
                                                    int* __restrict__ cnt,
                                                    int* __restrict__ rk) {
    const int i = blockIdx.x * 256 + threadIdx.x;  // < NN*32 exactly
    const float4 v = x[i];
    if (i < EE) rk[i] = atomicAdd(&cnt[dst[i] * R + et[i]], 1);
    xb[i * 2] = (u32)f2bf(v.x) | ((u32)f2bf(v.y) << 16);
    xb[i * 2 + 1] = (u32)f2bf(v.z) | ((u32)f2bf(v.w) << 16);
}

__global__ __launch_bounds__(256) void scanA(const int* __restrict__ cnt,
                                             int* __restrict__ off,
                                             int* __restrict__ bsum) {
    __shared__ int ts[256];
    const int b = blockIdx.x, t = threadIdx.x;
    const int base = b * SCAN_CHUNK + t * 4;
    int v0 = 0, v1 = 0, v2 = 0, v3 = 0;
    if (base + 3 < NR) {
        int4 q = *(const int4*)(cnt + base);
        v0 = q.x; v1 = q.y; v2 = q.z; v3 = q.w;
    } else {
        if (base < NR) v0 = cnt[base];
        if (base + 1 < NR) v1 = cnt[base + 1];
        if (base + 2 < NR) v2 = cnt[base + 2];
    }
    const int s = v0 + v1 + v2 + v3;
    ts[t] = s;
    __syncthreads();
    for (int d = 1; d < 256; d <<= 1) {
        int x = (t >= d) ? ts[t - d] : 0;
        __syncthreads();
        ts[t] += x;
        __syncthreads();
    }
    const int excl = ts[t] - s;
    if (base < NR) off[base] = excl;
    if (base + 1 < NR) off[base + 1] = excl + v0;
    if (base + 2 < NR) off[base + 2] = excl + v0 + v1;
    if (base + 3 < NR) off[base + 3] = excl + v0 + v1 + v2;
    if (t == 255) bsum[b] = ts[255];
}

__global__ __launch_bounds__(256) void scanBC(int* __restrict__ off,
                                              const int* __restrict__ bsum) {
    __shared__ int red[256];
    const int b = blockIdx.x, t = threadIdx.x;
    int p = 0;
    for (int i = t; i < b; i += 256) p += bsum[i];
    red[t] = p;
    __syncthreads();
    for (int d = 128; d > 0; d >>= 1) {
        if (t < d) red[t] += red[t + d];
        __syncthreads();
    }
    const int add = red[0];
    const int base = b * SCAN_CHUNK + t * 4;
#pragma unroll
    for (int j = 0; j < 4; ++j)
        if (base + j < NR) off[base + j] += add;
    if (b == 0 && t == 0) off[NR] = EE;
}

__global__ __launch_bounds__(256) void place2_kernel(const int* __restrict__ src,
                                                     const int* __restrict__ dst,
                                                     const int* __restrict__ et,
                                                     const int* __restrict__ off,
                                                     const int* __restrict__ rk,
                                                     u32* __restrict__ epk, int E) {
    int e = blockIdx.x * 256 + threadIdx.x;
    if (e < E) {
        const int r = et[e];
        const int p = off[dst[e] * R + r] + rk[e];
        epk[p] = ((u32)src[e] << 3) | (u32)r;
    }
}

// ---- pack both layers' B = [W_1..W_8; root] into MFMA B-frag order:
// [kt(36)][g(8)][lane(64)][j(8)], col = g*16+(lane&15), k = kt*32+(lane>>4)*8+j.
// Also zero cnt_i (must precede prep2's atomics; dispatch boundary). ----
__global__ __launch_bounds__(256) void bprep2_kernel(const float* __restrict__ w1,
                                                     const float* __restrict__ root1,
                                                     u16* __restrict__ Bf1,
                                                     const float* __restrict__ w2,
                                                     const float* __restrict__ root2,
                                                     u16* __restrict__ Bf2,
                                                     int4* __restrict__ cntz) {
    int gidx = blockIdx.x * 256 + threadIdx.x;  // over 2*36*8*64 = 36864
    for (int i = gidx; i < NR / 4; i += 36864)
        cntz[i] = make_int4(0, 0, 0, 0);
    if (gidx >= 2 * KT * 8 * 64) return;
    const int layer = gidx / (KT * 8 * 64);
    const int idx = gidx - layer * (KT * 8 * 64);
    const float* w = layer ? w2 : w1;
    const float* root = layer ? root2 : root1;
    u16* Bfrag = layer ? Bf2 : Bf1;
    const int lane = idx & 63;
    const int g = (idx >> 6) & 7;
    const int kt = idx >> 9;  // 0..35
    const int col = g * 16 + (lane & 15);
    const int kbase = kt * 32 + (lane >> 4) * 8;
    u16* o = Bfrag + (size_t)idx * 8;
#pragma unroll
    for (int j = 0; j < 8; ++j) {
        const int k = kbase + j;
        float v = (k < R * D) ? w[(size_t)(k >> 7) * (D * D) + (size_t)(k & 127) * D + col]
                              : root[(size_t)(k - R * D) * D + col];
        o[j] = f2bf(v);
    }
}

// ---- fused RGCN layer (round 10: ds_fadd + VECTOR-load epk window) ----
// Round-8/9 lesson: scalar epk loads (s_load) share lgkmcnt with the DS
// queue -> the compiler's lgkmcnt(0) before each batch's epk use drained all
// prior ds_add_f32 atomics (in-order lgkm), exposing LDS-atomic retire
// latency every 8 edges: 475us at VALUBusy 6.6%. Fix: round-5's sliding
// 128-edge epk window (VECTOR loads -> vmcnt domain) + readlane selection.
// Loop now has ZERO lgkm consumers: ds_adds retire fully async; only the
// phase barrier waits lgkmcnt(0) once.
// Phase 1: LDS f32 accumulator F[9][16][128] (rel-major; rel 8 = root). Per
// edge: pk via RDL from window (SGPR), 1 gather, node select = 1 scalar cmp
// vs eM, 2 fire-and-forget ds_add_f32; ~8 VALU/edge, no segment state, all
// edges independent. Column XOR swizzle col = lane ^ ((node&7)<<2)
// (bijective, verified r8/r9); lo cols [0..63]=even dims, hi [64..127]=odd;
// phase-2 rebuilds bf16 pairs via v_cvt_pk_bf16_f32. Mean scaling deferred
// to phase 2 (per-lane inv[8], full unroll). LDS 74KB -> 2 blocks/CU.
template <bool OUTBF>
__global__ __launch_bounds__(512, 4) void rgcn_fused(const u32* __restrict__ xb,
                                                     const u16* __restrict__ Bf,
                                                     const int* __restrict__ off,
                                                     const u32* __restrict__ epk,
                                                     const float* __restrict__ bias,
                                                     void* __restrict__ outp) {
    __shared__ float Fs[9 * 16 * 128];   // 73728 B
    __shared__ float inv_lds[16][8];     // 512 B

    const int t = threadIdx.x;
    const int wid = t >> 6;
    const int lane = t & 63;
    const int n0 = blockIdx.x * 16;

    // zero F (empty segments must contribute 0)
    {
        uint4* Fz = (uint4*)Fs;
        for (int i = t; i < 4608; i += 512) Fz[i] = make_uint4(0, 0, 0, 0);
    }
    __syncthreads();

    const int i0 = wid * 2;              // this wave's 2 local node slots
    const int nb = n0 + i0;              // < NN always (50000 = 16*3125)

    // 17 boundaries for 2 nodes (one clamped load; off[NR] = EE)
    int offv;
    {
        int oi = nb * 8 + lane;
        if (oi > NR) oi = NR;
        offv = off[oi];
    }

    // per-(node,rel) inverse counts -> inv_lds
    {
        const int cnext = __shfl(offv, lane + 1);
        if (lane < 16) {
            const int c = cnext - offv;
            inv_lds[i0 + (lane >> 3)][lane & 7] = (c > 0) ? 1.0f / (float)c : 0.f;
        }
    }

    // root rows -> F rel=8 (plain stores, each slot owned by one wave)
    {
        const u32 rv0 = xb[(size_t)nb * 64 + lane];
        const u32 rv1 = xb[(size_t)(nb + 1) * 64 + lane];
        const int c0 = lane ^ ((i0 & 7) << 2);
        const int c1 = lane ^ (((i0 + 1) & 7) << 2);
        union { u32 u; float f; } lo_, hi_;
        lo_.u = rv0 << 16; hi_.u = rv0 & 0xFFFF0000u;
        Fs[16384 + i0 * 128 + c0] = lo_.f;
        Fs[16384 + i0 * 128 + c0 + 64] = hi_.f;
        lo_.u = rv1 << 16; hi_.u = rv1 & 0xFFFF0000u;
        Fs[16384 + (i0 + 1) * 128 + c1] = lo_.f;
        Fs[16384 + (i0 + 1) * 128 + c1 + 64] = hi_.f;
    }

    const int e0 = RDL(offv, 0);
    const int eM = RDL(offv, 8);   // node boundary
    const int e1 = RDL(offv, 16);

    // per-node swizzled LDS bases (VGPR; selected per edge by scalar cmp)
    const int nbase0 = i0 * 128 + (lane ^ ((i0 & 7) << 2));
    const int nbase1 = (i0 + 1) * 128 + (lane ^ (((i0 + 1) & 7) << 2));

    // sliding 128-edge epk window in 2 regs (vector loads, vmcnt domain)
    int wb = e0;
    u32 w0, w1;
    {
        int ia = e0 + lane; if (ia >= EE) ia = EE - 1;
        int ib = e0 + 64 + lane; if (ib >= EE) ib = EE - 1;
        w0 = epk[ia];
        w1 = epk[ib];
    }

#define PREF1(k_, d_, pp)                                                      \
    do {                                                                       \
        const int j_ = (pp) - wb;                                              \
        k_ = (u32)((j_ < 64) ? RDL(w0, j_) : RDL(w1, j_ - 64));                \
        d_ = xb[(size_t)(k_ >> 3) * 64 + lane];                                \
    } while (0)

#define PROCE(k_, v_, pp)                                                      \
    do {                                                                       \
        if ((pp) < e1) {                                                       \
            const int nb_ = ((pp) < eM) ? nbase0 : nbase1;                     \
            const int fb_ = (int)((k_) & 7u) * 2048 + nb_;                     \
            union { u32 u; float f; } lo_, hi_;                                \
            lo_.u = (v_) << 16; hi_.u = (v_) & 0xFFFF0000u;                    \
            ds_fadd(&Fs[fb_], lo_.f);                                          \
            ds_fadd(&Fs[fb_ + 64], hi_.f);                                     \
        }                                                                      \
    } while (0)

    // ---- edge stream: batches of 4, 3 batches in flight ----
    int p = e0;
    u32 k0, k1, k2, k3, ka0, ka1, ka2, ka3, kb0, kb1, kb2, kb3;
    u32 a0, a1, a2, a3, b0, b1, b2, b3, c0, c1, c2, c3;
    PREF1(k0, a0, p);      PREF1(k1, a1, p + 1);
    PREF1(k2, a2, p + 2);  PREF1(k3, a3, p + 3);
    PREF1(ka0, b0, p + 4); PREF1(ka1, b1, p + 5);
    PREF1(ka2, b2, p + 6); PREF1(ka3, b3, p + 7);
    const int nbt = (e1 - e0 + 3) >> 2;
#pragma unroll 1
    for (int bt = 0; bt < nbt; ++bt) {
        if (p + 8 - wb >= 64) {  // slide window
            wb += 64; w0 = w1;
            int ia = wb + 64 + lane; if (ia >= EE) ia = EE - 1;
            w1 = epk[ia];
        }
        PREF1(kb0, c0, p + 8);  PREF1(kb1, c1, p + 9);
        PREF1(kb2, c2, p + 10); PREF1(kb3, c3, p + 11);
        PROCE(k0, a0, p);     PROCE(k1, a1, p + 1);
        PROCE(k2, a2, p + 2); PROCE(k3, a3, p + 3);
        p += 4;
        k0 = ka0; k1 = ka1; k2 = ka2; k3 = ka3;
        a0 = b0; a1 = b1; a2 = b2; a3 = b3;
        ka0 = kb0; ka1 = kb1; ka2 = kb2; ka3 = kb3;
        b0 = c0; b1 = c1; b2 = c2; b3 = c3;
    }

#undef PREF1
#undef PROCE
    __syncthreads();

    // ---- phase 2: wave g -> col-tile g; A from F (convert on the fly) ----
    const int g = wid;
    const int node = lane & 15;
    const int quad = lane >> 4;
    const int swz = (node & 7) << 2;
    const int quad4 = quad * 4;
    const int nrow = node * 128;

    float vinv[8];
    {
        const float4 ia = *(const float4*)&inv_lds[node][0];
        const float4 ib = *(const float4*)&inv_lds[node][4];
        vinv[0] = ia.x; vinv[1] = ia.y; vinv[2] = ia.z; vinv[3] = ia.w;
        vinv[4] = ib.x; vinv[5] = ib.y; vinv[6] = ib.z; vinv[7] = ib.w;
    }

    f32x4 acc = {0.f, 0.f, 0.f, 0.f};
    const u16* bp = Bf + ((size_t)g * 64 + lane) * 8;
#pragma unroll
    for (int kt = 0; kt < KT; ++kt) {
        const int rel = kt >> 2, kc = kt & 3;
        const bf16x8 b = *(const bf16x8*)(bp + (size_t)kt * 4096);
        const int cidx = nrow + ((kc * 16 + quad4) ^ swz);
        const float4 lo = *(const float4*)&Fs[cidx + rel * 2048];
        const float4 hi = *(const float4*)&Fs[cidx + rel * 2048 + 64];
        float l0 = lo.x, l1 = lo.y, l2 = lo.z, l3 = lo.w;
        float h0 = hi.x, h1 = hi.y, h2 = hi.z, h3 = hi.w;
        if (rel < 8) {
            const float s = vinv[rel];
            l0 *= s; l1 *= s; l2 *= s; l3 *= s;
            h0 *= s; h1 *= s; h2 *= s; h3 *= s;
        }
        union { u32 q[4]; bf16x8 v; } U;
        U.q[0] = cvtpk(l0, h0); U.q[1] = cvtpk(l1, h1);
        U.q[2] = cvtpk(l2, h2); U.q[3] = cvtpk(l3, h3);
        acc = __builtin_amdgcn_mfma_f32_16x16x32_bf16(U.v, b, acc, 0, 0, 0);
    }

    // ---- epilogue: C row=(lane>>4)*4+q, col=g*16+(lane&15); no tail ----
    const int col = g * 16 + (lane & 15);
    const float bb = bias[col];
#pragma unroll
    for (int q = 0; q < 4; ++q) {
        const int row = n0 + quad * 4 + q;
        const float v = fmaxf(acc[q] + bb, 0.f);
        if (OUTBF)
            ((u16*)outp)[(size_t)row * D + col] = f2bf(v);
        else
            ((float*)outp)[(size_t)row * D + col] = v;
    }
}

extern "C" void kernel_launch(void* const* d_in, const int* in_sizes, int n_in,
                              void* d_out, int out_size, void* d_ws, size_t ws_size,
                              hipStream_t stream) {
    const float* x = (const float*)d_in[0];
    const int* ei = (const int*)d_in[1];
    const int* et = (const int*)d_in[2];
    const float* w1 = (const float*)d_in[3];
    const float* root1 = (const float*)d_in[4];
    const float* b1 = (const float*)d_in[5];
    const float* w2 = (const float*)d_in[6];
    const float* root2 = (const float*)d_in[7];
    const float* b2 = (const float*)d_in[8];
    float* out = (float*)d_out;

    char* ws = (char*)d_ws;
    int* off    = (int*)(ws + 0);                  // (NR+1) ints
    int* cnt_i  = (int*)(ws + 1600512);            // NR ints
    int* rk     = (int*)(ws + 3200512);            // EE ints (edge rank)
    int* bsum   = (int*)(ws + 5600512);            // NSB ints
    u32* epk    = (u32*)(ws + 5604096);            // EE u32 (2.4 MB)
    u32* xb     = (u32*)(ws + 8004096);            // N*64 u32 = 12.8 MB
    u32* h      = (u32*)(ws + 20804096);           // N*64 u32 = 12.8 MB
    u16* Bf1    = (u16*)(ws + 33604096);           // 294912 B
    u16* Bf2    = (u16*)(ws + 33899008);           // 294912 B

    const int* srcp = ei;
    const int* dstp = ei + EE;

    // ---- prep (round-5 structure): pack B + zero cnt; {xcast ∥ hist+rank};
    // scan; place ----
    bprep2_kernel<<<144, 256, 0, stream>>>(w1, root1, Bf1, w2, root2, Bf2,
                                           (int4*)cnt_i);
    prep2_kernel<<<NN * 32 / 256, 256, 0, stream>>>((const float4*)x, xb,
                                                    dstp, et, cnt_i, rk);
    scanA<<<NSB, 256, 0, stream>>>(cnt_i, off, bsum);
    scanBC<<<NSB, 256, 0, stream>>>(off, bsum);
    place2_kernel<<<(EE + 255) / 256, 256, 0, stream>>>(srcp, dstp, et, off, rk,
                                                        epk, EE);

    const int fused_blocks = NN / 16;  // 3125, exact

    // layer 1: xb -> h (bf16)
    rgcn_fused<true><<<fused_blocks, 512, 0, stream>>>(xb, Bf1, off, epk, b1,
                                                       (void*)h);
    // layer 2: h -> out (fp32)
    rgcn_fused<false><<<fused_blocks, 512, 0, stream>>>(h, Bf2, off, epk, b2,
                                                        (void*)out);
}

// Round 11
// 276.176 us; speedup vs baseline: 3.7958x; 3.7165x over previous
//
#include <hip/hip_runtime.h>

#define NN 50000
#define D 128
#define EE 600000
#define R 8
#define NR (NN * R)            /* segments, key = dst*R + rel (node-major) */
#define SCAN_CHUNK 1024
#define NSB ((NR + SCAN_CHUNK - 1) / SCAN_CHUNK) /* 391 */
#define KT 36                  /* K tiles: (8*128 + 128)/32 */

typedef unsigned short u16;
typedef unsigned int u32;
typedef __attribute__((ext_vector_type(8))) short bf16x8;
typedef __attribute__((ext_vector_type(4))) float f32x4;

#define RDL(v_, i_) __builtin_amdgcn_readlane((int)(v_), (i_))

__device__ inline u16 f2bf(float f) {
    union { float f; u32 u; } v; v.f = f;
    return (u16)((v.u + 0x7FFFu + ((v.u >> 16) & 1u)) >> 16);
}

// ---- prep (round-5 proven versions) ----

// cast x fp32->bf16 pairs AND histogram+rank in one dispatch (6250 blocks)
__global__ __launch_bounds__(256) void prep2_kernel(const float4* __restrict__ x,
                                                    u32* __restrict__ xb,
                                                    const int* __restrict__ dst,
                                                    const int* __restrict__ et,
                                                    int* __restrict__ cnt,
                                                    int* __restrict__ rk) {
    const int i = blockIdx.x * 256 + threadIdx.x;  // < NN*32 exactly
    const float4 v = x[i];
    if (i < EE) rk[i] = atomicAdd(&cnt[dst[i] * R + et[i]], 1);
    xb[i * 2] = (u32)f2bf(v.x) | ((u32)f2bf(v.y) << 16);
    xb[i * 2 + 1] = (u32)f2bf(v.z) | ((u32)f2bf(v.w) << 16);
}

__global__ __launch_bounds__(256) void scanA(const int* __restrict__ cnt,
                                             int* __restrict__ off,
                                             int* __restrict__ bsum) {
    __shared__ int ts[256];
    const int b = blockIdx.x, t = threadIdx.x;
    const int base = b * SCAN_CHUNK + t * 4;
    int v0 = 0, v1 = 0, v2 = 0, v3 = 0;
    if (base + 3 < NR) {
        int4 q = *(const int4*)(cnt + base);
        v0 = q.x; v1 = q.y; v2 = q.z; v3 = q.w;
    } else {
        if (base < NR) v0 = cnt[base];
        if (base + 1 < NR) v1 = cnt[base + 1];
        if (base + 2 < NR) v2 = cnt[base + 2];
    }
    const int s = v0 + v1 + v2 + v3;
    ts[t] = s;
    __syncthreads();
    for (int d = 1; d < 256; d <<= 1) {
        int x = (t >= d) ? ts[t - d] : 0;
        __syncthreads();
        ts[t] += x;
        __syncthreads();
    }
    const int excl = ts[t] - s;
    if (base < NR) off[base] = excl;
    if (base + 1 < NR) off[base + 1] = excl + v0;
    if (base + 2 < NR) off[base + 2] = excl + v0 + v1;
    if (base + 3 < NR) off[base + 3] = excl + v0 + v1 + v2;
    if (t == 255) bsum[b] = ts[255];
}

__global__ __launch_bounds__(256) void scanBC(int* __restrict__ off,
                                              const int* __restrict__ bsum) {
    __shared__ int red[256];
    const int b = blockIdx.x, t = threadIdx.x;
    int p = 0;
    for (int i = t; i < b; i += 256) p += bsum[i];
    red[t] = p;
    __syncthreads();
    for (int d = 128; d > 0; d >>= 1) {
        if (t < d) red[t] += red[t + d];
        __syncthreads();
    }
    const int add = red[0];
    const int base = b * SCAN_CHUNK + t * 4;
#pragma unroll
    for (int j = 0; j < 4; ++j)
        if (base + j < NR) off[base + j] += add;
    if (b == 0 && t == 0) off[NR] = EE;
}

__global__ __launch_bounds__(256) void place2_kernel(const int* __restrict__ src,
                                                     const int* __restrict__ dst,
                                                     const int* __restrict__ et,
                                                     const int* __restrict__ off,
                                                     const int* __restrict__ rk,
                                                     u32* __restrict__ epk, int E) {
    int e = blockIdx.x * 256 + threadIdx.x;
    if (e < E) {
        const int r = et[e];
        const int p = off[dst[e] * R + r] + rk[e];
        epk[p] = ((u32)src[e] << 3) | (u32)r;
    }
}

// ---- pack both layers' B = [W_1..W_8; root] into MFMA B-frag order:
// [kt(36)][g(8)][lane(64)][j(8)], col = g*16+(lane&15), k = kt*32+(lane>>4)*8+j.
// Also zero cnt_i (must precede prep2's atomics; dispatch boundary). ----
__global__ __launch_bounds__(256) void bprep2_kernel(const float* __restrict__ w1,
                                                     const float* __restrict__ root1,
                                                     u16* __restrict__ Bf1,
                                                     const float* __restrict__ w2,
                                                     const float* __restrict__ root2,
                                                     u16* __restrict__ Bf2,
                                                     int4* __restrict__ cntz) {
    int gidx = blockIdx.x * 256 + threadIdx.x;  // over 2*36*8*64 = 36864
    for (int i = gidx; i < NR / 4; i += 36864)
        cntz[i] = make_int4(0, 0, 0, 0);
    if (gidx >= 2 * KT * 8 * 64) return;
    const int layer = gidx / (KT * 8 * 64);
    const int idx = gidx - layer * (KT * 8 * 64);
    const float* w = layer ? w2 : w1;
    const float* root = layer ? root2 : root1;
    u16* Bfrag = layer ? Bf2 : Bf1;
    const int lane = idx & 63;
    const int g = (idx >> 6) & 7;
    const int kt = idx >> 9;  // 0..35
    const int col = g * 16 + (lane & 15);
    const int kbase = kt * 32 + (lane >> 4) * 8;
    u16* o = Bfrag + (size_t)idx * 8;
#pragma unroll
    for (int j = 0; j < 8; ++j) {
        const int k = kbase + j;
        float v = (k < R * D) ? w[(size_t)(k >> 7) * (D * D) + (size_t)(k & 127) * D + col]
                              : root[(size_t)(k - R * D) * D + col];
        o[j] = f2bf(v);
    }
}

// ---- fused RGCN layer (round 11: r5 register machinery, 16 waves x 1 node) ----
// Rounds 8-10 lesson: wave64 LDS FP atomics serialize ~200 cyc each -> dead
// path. Reverted to round-5's register accumulation + segment flush (proven
// 65.6us @ VALUBusy 59%), and attacked its residual ~2x stall = serial-chain
// length + degree straggle: 16 waves x ONE node (~12-edge chain) instead of
// 8 waves x 2 nodes (~24-edge chain). 1024-thread blocks, 2/CU = full 2048
// threads; 50k phase-1 chains grid-wide (Little's law: same issue work, half
// the exposed latency). Phase 2 split-K: wave = (g, half); each half does 18
// of 36 K-tiles; half-1 parks its partial acc in an 8KB LDS scratch; one
// barrier; half-0 adds it and runs the epilogue.
// phase 1 per wave: ONE contiguous edge stream for its node's 8 segments;
//   ALL loads unconditional (clamped; counted vmcnt preserved); scalar
//   (readlane) loop state -> s_cbranch only; 3-batch x4 rotation = 12
//   gathers in flight; segment mean flushed to the A-frag LDS slot (wbase
//   now hoisted: node fixed per wave).
template <bool OUTBF>
__global__ __launch_bounds__(1024, 2) void rgcn_fused(const u32* __restrict__ xb,
                                                      const u16* __restrict__ Bf,
                                                      const int* __restrict__ off,
                                                      const u32* __restrict__ epk,
                                                      const float* __restrict__ bias,
                                                      void* __restrict__ outp) {
    __shared__ u32 A32[KT * 256];   // 36864 B
    __shared__ f32x4 pscr[512];     // 8192 B split-K partials [g][lane]

    const int t = threadIdx.x;
    const int wid = t >> 6;          // 0..15
    const int lane = t & 63;
    const int n0 = blockIdx.x * 16;

    const int q2 = (lane & 15) >> 2;
    const int ktl = lane >> 4;
    const int xv = q2 | ((ktl & 1) << 2);  // swizzle term (3 bits)

    // zero A (empty segments must read 0 in phase 2)
    {
        uint4* Az = (uint4*)A32;
        for (int i = t; i < (KT * 256) / 4; i += 1024)
            Az[i] = make_uint4(0, 0, 0, 0);
    }
    __syncthreads();

    const int iw = wid;              // local node slot 0..15
    const int nb = n0 + iw;          // < NN always (50000 = 16*3125)

    // 9 boundaries for this node (one clamped unconditional load; off[NR]=EE)
    int offv;
    {
        int oi = nb * 8 + lane;
        if (oi > NR) oi = NR;
        offv = off[oi];
    }
    const int e0 = RDL(offv, 0);
    const int e1 = RDL(offv, 8);

    // root row (independent, issued early)
    const u32 rv0 = xb[(size_t)nb * 64 + lane];

    // sliding 128-edge epk window in 2 regs (unconditional clamped loads)
    int wb = e0;
    u32 w0, w1;
    {
        int ia = e0 + lane; if (ia >= EE) ia = EE - 1;
        int ib = e0 + 64 + lane; if (ib >= EE) ib = EE - 1;
        w0 = epk[ia];
        w1 = epk[ib];
    }

    // segment state (all scalar); A-slot base hoisted (node fixed per wave)
    const int wbase = (((iw ^ xv) + 16 * q2) << 2) + (lane & 3);
    int seg = 0;
    while (seg < 8 && RDL(offv, seg + 1) <= e0) ++seg;
    int segEnd = (seg < 8) ? RDL(offv, seg + 1) : 0x7FFFFFFF;
    int segStart = e0;
    float sx = 0.f, sy = 0.f;

#define FLUSH(pp)                                                              \
    do {                                                                       \
        const float inv_ = 1.f / (float)((pp) - segStart);                     \
        A32[(seg * 4 + ktl) * 256 + wbase] =                                   \
            (u32)f2bf(sx * inv_) | ((u32)f2bf(sy * inv_) << 16);               \
        sx = 0.f; sy = 0.f; segStart = (pp);                                   \
        ++seg;                                                                 \
        while (seg < 8 && RDL(offv, seg + 1) <= (pp)) ++seg;                   \
        segEnd = (seg < 8) ? RDL(offv, seg + 1) : 0x7FFFFFFF;                  \
    } while (0)

#define PREF1(d_, pp)                                                          \
    do {                                                                       \
        const int j_ = (pp) - wb;                                              \
        const u32 pk_ = (u32)((j_ < 64) ? RDL(w0, j_) : RDL(w1, j_ - 64));     \
        d_ = xb[(size_t)(pk_ >> 3) * 64 + lane];                               \
    } while (0)

#define PROC1(v_, pp)                                                          \
    do {                                                                       \
        if ((pp) == segEnd) FLUSH(pp);                                         \
        if ((pp) < e1) {                                                       \
            union { u32 u; float f; } lo_, hi_;                                \
            lo_.u = (v_) << 16;                                                \
            hi_.u = (v_) & 0xFFFF0000u;                                        \
            sx += lo_.f;                                                       \
            sy += hi_.f;                                                       \
        }                                                                      \
    } while (0)

    // ---- edge stream: batches of 4, 3 batches in flight ----
    int p = e0;
    u32 a0, a1, a2, a3, b0, b1, b2, b3, c0, c1, c2, c3;
    PREF1(a0, p);     PREF1(a1, p + 1); PREF1(a2, p + 2); PREF1(a3, p + 3);
    PREF1(b0, p + 4); PREF1(b1, p + 5); PREF1(b2, p + 6); PREF1(b3, p + 7);
    const int nbt = (e1 - e0 + 3) >> 2;
#pragma unroll 1
    for (int bt = 0; bt < nbt; ++bt) {
        if (p + 8 - wb >= 64) {  // slide window
            wb += 64; w0 = w1;
            int ia = wb + 64 + lane; if (ia >= EE) ia = EE - 1;
            w1 = epk[ia];
        }
        PREF1(c0, p + 8); PREF1(c1, p + 9); PREF1(c2, p + 10); PREF1(c3, p + 11);
        PROC1(a0, p); PROC1(a1, p + 1); PROC1(a2, p + 2); PROC1(a3, p + 3);
        p += 4;
        a0 = b0; a1 = b1; a2 = b2; a3 = b3;
        b0 = c0; b1 = c1; b2 = c2; b3 = c3;
    }
    if (seg < 8 && segStart < e1) FLUSH(e1);  // final open segment

#undef FLUSH
#undef PREF1
#undef PROC1

    // root section: kt = 32 + ktl
    A32[(32 + ktl) * 256 + wbase] = rv0;
    __syncthreads();

    // ---- phase 2 split-K: wave (g, half) does K-tiles [half*18, half*18+18) ----
    const int g = wid & 7;
    const int half = wid >> 3;
    f32x4 acc = {0.f, 0.f, 0.f, 0.f};
    const u16* bp = Bf + ((size_t)g * 64 + lane) * 8;
    const u16* A16 = (const u16*)A32;
    const int kt0 = half * 18;
#pragma unroll
    for (int k = 0; k < 18; ++k) {
        const int kt = kt0 + k;   // kt0 even -> kt&1 == k&1 (compile-time)
        const bf16x8 b = *(const bf16x8*)(bp + (size_t)kt * 4096);
        const int xvr = (lane >> 4) | ((k & 1) << 2);
        const int lp = (lane ^ xvr) * 8;
        const bf16x8 fa = *(const bf16x8*)(A16 + kt * 512 + lp);
        acc = __builtin_amdgcn_mfma_f32_16x16x32_bf16(fa, b, acc, 0, 0, 0);
    }
    if (half == 1) pscr[g * 64 + lane] = acc;
    __syncthreads();

    if (half == 0) {
        const f32x4 o = pscr[g * 64 + lane];
        // ---- epilogue: C row=(lane>>4)*4+q, col=g*16+(lane&15); no tail ----
        const int quad = lane >> 4;
        const int col = g * 16 + (lane & 15);
        const float bb = bias[col];
#pragma unroll
        for (int q = 0; q < 4; ++q) {
            const int row = n0 + quad * 4 + q;
            const float v = fmaxf(acc[q] + o[q] + bb, 0.f);
            if (OUTBF)
                ((u16*)outp)[(size_t)row * D + col] = f2bf(v);
            else
                ((float*)outp)[(size_t)row * D + col] = v;
        }
    }
}

extern "C" void kernel_launch(void* const* d_in, const int* in_sizes, int n_in,
                              void* d_out, int out_size, void* d_ws, size_t ws_size,
                              hipStream_t stream) {
    const float* x = (const float*)d_in[0];
    const int* ei = (const int*)d_in[1];
    const int* et = (const int*)d_in[2];
    const float* w1 = (const float*)d_in[3];
    const float* root1 = (const float*)d_in[4];
    const float* b1 = (const float*)d_in[5];
    const float* w2 = (const float*)d_in[6];
    const float* root2 = (const float*)d_in[7];
    const float* b2 = (const float*)d_in[8];
    float* out = (float*)d_out;

    char* ws = (char*)d_ws;
    int* off    = (int*)(ws + 0);                  // (NR+1) ints
    int* cnt_i  = (int*)(ws + 1600512);            // NR ints
    int* rk     = (int*)(ws + 3200512);            // EE ints (edge rank)
    int* bsum   = (int*)(ws + 5600512);            // NSB ints
    u32* epk    = (u32*)(ws + 5604096);            // EE u32 (2.4 MB)
    u32* xb     = (u32*)(ws + 8004096);            // N*64 u32 = 12.8 MB
    u32* h      = (u32*)(ws + 20804096);           // N*64 u32 = 12.8 MB
    u16* Bf1    = (u16*)(ws + 33604096);           // 294912 B
    u16* Bf2    = (u16*)(ws + 33899008);           // 294912 B

    const int* srcp = ei;
    const int* dstp = ei + EE;

    // ---- prep (round-5 structure): pack B + zero cnt; {xcast ∥ hist+rank};
    // scan; place ----
    bprep2_kernel<<<144, 256, 0, stream>>>(w1, root1, Bf1, w2, root2, Bf2,
                                           (int4*)cnt_i);
    prep2_kernel<<<NN * 32 / 256, 256, 0, stream>>>((const float4*)x, xb,
                                                    dstp, et, cnt_i, rk);
    scanA<<<NSB, 256, 0, stream>>>(cnt_i, off, bsum);
    scanBC<<<NSB, 256, 0, stream>>>(off, bsum);
    place2_kernel<<<(EE + 255) / 256, 256, 0, stream>>>(srcp, dstp, et, off, rk,
                                                        epk, EE);

    const int fused_blocks = NN / 16;  // 3125, exact

    // layer 1: xb -> h (bf16)
    rgcn_fused<true><<<fused_blocks, 1024, 0, stream>>>(xb, Bf1, off, epk, b1,
                                                        (void*)h);
    // layer 2: h -> out (fp32)
    rgcn_fused<false><<<fused_blocks, 1024, 0, stream>>>(h, Bf2, off, epk, b2,
                                                         (void*)out);
}